// Round 10
// baseline (1011.722 us; speedup 1.0000x reference)
//
#include <hip/hip_runtime.h>
#include <hip/hip_bf16.h>

#define DIMN 1024
#define IMG_H 512
#define IMG_W 1408
#define CROPN 224
#define NCAM 6
#define NBOXB 32
#define NBOX 64            // NBATCH*NBOXB
#define NIMG 384           // NBOX*NCAM

typedef __hip_bfloat16 bf16;
typedef unsigned short u16;
typedef float f32x4 __attribute__((ext_vector_type(4)));
typedef short bf16x8 __attribute__((ext_vector_type(8)));
typedef u16 u16x4 __attribute__((ext_vector_type(4)));
typedef u16 u16x8 __attribute__((ext_vector_type(8)));

__device__ __forceinline__ float b2f(bf16 x) { return __bfloat162float(x); }
__device__ __forceinline__ u16 f2us(float x) {
  bf16 h = __float2bfloat16(x);
  return *(u16*)&h;
}
__device__ __forceinline__ bf16x8 as_b(u16x8 x) {
  union { u16x8 u; bf16x8 b; } c; c.u = x; return c.b;
}

// ---------------- prep: weight reorders (K-order = (r,kw),ic  channel-last) ----------------
// conv1 (64,3,7,7) -> fragment-contiguous W1f[ocb=oc>>4][kb=K>>3][m=oc&15][kj=K&7]
// K = r*32 + kw*4 + ch (kw<7, ch<3 else 0). A-frag load = 1KB contiguous per wave.
__global__ void k_w1r(const float* __restrict__ in, u16* __restrict__ out) {
  int idx = blockIdx.x * 256 + threadIdx.x;
  if (idx >= 64 * 224) return;
  int oc = idx / 224, t = idx % 224;
  int r = t >> 5, u = t & 31, kw = u >> 2, ch = u & 3;
  u16 v = (kw < 7 && ch < 3) ? f2us(in[((oc * 3 + ch) * 7 + r) * 7 + kw]) : (u16)0;
  out[(((oc >> 4) * 28 + (t >> 3)) * 16 + (oc & 15)) * 8 + (t & 7)] = v;
}
// conv2 (256,64,3,3) -> fragment-contiguous W2f[ocb=oc>>4][kb=K>>3][m=oc&15][kj=K&7]
// K = (r*3+kw)*64 + ic
__global__ void k_w2r(const float* __restrict__ in, u16* __restrict__ out) {
  int idx = blockIdx.x * 256 + threadIdx.x;
  if (idx >= 256 * 576) return;
  int oc = idx / 576, t = idx % 576;
  int rk = t >> 6, ic = t & 63, r = rk / 3, kw = rk % 3;
  u16 v = f2us(in[((oc * 64 + ic) * 3 + r) * 3 + kw]);
  out[(((oc >> 4) * 72 + (t >> 3)) * 16 + (oc & 15)) * 8 + (t & 7)] = v;
}
// conv3 (1024,256,3,3) -> fragment-contiguous layout:
// W3f[ocblk=oc>>4][kblk=K>>3][m=oc&15][kj=K&7], K = (r*3+kw)*256 + ic
__global__ void k_w3r(const float* __restrict__ in, u16* __restrict__ out) {
  int idx = blockIdx.x * 256 + threadIdx.x;
  if (idx >= 1024 * 2304) return;
  int oc = idx / 2304, t = idx % 2304;
  int rk = t >> 8, ic = t & 255, r = rk / 3, kw = rk % 3;
  u16 v = f2us(in[((oc * 256 + ic) * 3 + r) * 3 + kw]);
  int ocb = oc >> 4, mm = oc & 15, kb = t >> 3, kj = t & 7;
  out[(((size_t)ocb * 288 + kb) * 16 + mm) * 8 + kj] = v;
}
// tiled transpose 1024x1024 f32 (wk -> wkT)
__global__ void k_transpose_t(const float* __restrict__ w, float* __restrict__ wt) {
  __shared__ float tile[32][33];
  int x = blockIdx.x * 32 + threadIdx.x;
  for (int j = threadIdx.y; j < 32; j += 8)
    tile[j][threadIdx.x] = w[(size_t)(blockIdx.y * 32 + j) * 1024 + x];
  __syncthreads();
  int x2 = blockIdx.y * 32 + threadIdx.x;
  for (int j = threadIdx.y; j < 32; j += 8)
    wt[(size_t)(blockIdx.x * 32 + j) * 1024 + x2] = tile[threadIdx.x][j];
}

// ---------------- projection + theta ----------------
__global__ void k_proj(const float* __restrict__ boxes, const float* __restrict__ la_m,
                       const float* __restrict__ l2i, const float* __restrict__ aug,
                       const float* __restrict__ tw, const float* __restrict__ tb,
                       float* __restrict__ theta_out, int* __restrict__ valid_out) {
  int t = threadIdx.x;
  if (t >= NIMG) return;
  int n = t / NCAM, cam = t % NCAM;
  int b = n / NBOXB, nb = n % NBOXB;

  float la[4][4];
  for (int r = 0; r < 4; r++)
    for (int c = 0; c < 4; c++) la[r][c] = la_m[b * 16 + r * 4 + c];
  float a00=la[0][0],a01=la[0][1],a02=la[0][2];
  float a10=la[1][0],a11=la[1][1],a12=la[1][2];
  float a20=la[2][0],a21=la[2][1],a22=la[2][2];
  float c00 =  a11*a22 - a12*a21;
  float c01 = -(a10*a22 - a12*a20);
  float c02 =  a10*a21 - a11*a20;
  float det = a00*c00 + a01*c01 + a02*c02;
  float id = 1.0f / det;
  float inv[3][3];
  inv[0][0] = c00*id;                 inv[0][1] = -(a01*a22-a02*a21)*id;  inv[0][2] =  (a01*a12-a02*a11)*id;
  inv[1][0] = c01*id;                 inv[1][1] =  (a00*a22-a02*a20)*id;  inv[1][2] = -(a00*a12-a02*a10)*id;
  inv[2][0] = c02*id;                 inv[2][1] = -(a00*a21-a01*a20)*id;  inv[2][2] =  (a00*a11-a01*a10)*id;

  float bx[9];
  for (int i = 0; i < 9; i++) bx[i] = boxes[(b * NBOXB + nb) * 9 + i];
  float c0[3] = { bx[0]-la[0][3], bx[1]-la[1][3], bx[2]-la[2][3] };
  float c1[3];
  for (int r = 0; r < 3; r++) c1[r] = inv[r][0]*c0[0] + inv[r][1]*c0[1] + inv[r][2]*c0[2];

  const float* M = l2i + (size_t)(b * NCAM + cam) * 16;
  float p[3];
  for (int r = 0; r < 3; r++)
    p[r] = M[r*4+0]*c1[0] + M[r*4+1]*c1[1] + M[r*4+2]*c1[2] + M[r*4+3];
  float z = fminf(fmaxf(p[2], 1e-5f), 100000.0f);
  float x = p[0] / z, y = p[1] / z;
  const float* A = aug + (size_t)(b * NCAM + cam) * 16;
  float u = A[0]*x + A[1]*y + A[2]*z + A[3];
  float v = A[4]*x + A[5]*y + A[6]*z + A[7];

  int on = (v < (float)IMG_H) && (v >= 0.0f) && (u < (float)IMG_W) && (u >= 0.0f);
  float ty = v / (float)IMG_H * 2.0f - 1.0f;
  float tx = u / (float)IMG_W * 2.0f - 1.0f;

  float s[4];
  for (int j = 0; j < 4; j++) {
    float acc = tb[j];
    for (int i = 0; i < 9; i++) acc += tw[j * 9 + i] * bx[i];
    s[j] = tanhf(acc);
  }
  float* o = theta_out + t * 6;
  o[0] = s[0]; o[1] = s[1]; o[2] = tx;
  o[3] = s[2]; o[4] = s[3]; o[5] = ty;
  valid_out[t] = on;
}

// ---------------- zero the crop halo (rows/cols 0,225,226 of 228x228 ch-last buffer) ----------------
#define HALO_PX 1356   // 3*228 + 224*3
__global__ void k_zero_halo(u16x4* __restrict__ c) {
  int t = blockIdx.x * 256 + threadIdx.x;
  int i = t / HALO_PX;
  if (i >= NIMG) return;
  int r = t % HALO_PX;
  int ph, pw;
  if (r < 684) {
    int rr = r / 228;
    ph = (rr == 0) ? 0 : (rr == 1 ? 225 : 226);
    pw = r % 228;
  } else {
    int q = r - 684;
    ph = 1 + q / 3;
    int s = q % 3;
    pw = (s == 0) ? 0 : (s == 1 ? 225 : 226);
  }
  c[(size_t)i * 228 * 228 + ph * 228 + pw] = (u16x4){0, 0, 0, 0};
}

// ---------------- crop sampling -> channel-last halo'd crops [i][228][228][4] bf16 ----------------
__global__ __launch_bounds__(256) void k_sample(const float* __restrict__ imgs,
                                                const float* __restrict__ theta,
                                                u16* __restrict__ crops) {
  int idx = blockIdx.x * 256 + threadIdx.x;   // NIMG*224*224 exactly
  int i = idx / (CROPN * CROPN);
  int rem = idx - i * (CROPN * CROPN);
  int yy = rem / CROPN, xx = rem % CROPN;
  const float* th = theta + i * 6;
  float gx = (2.0f * xx + 1.0f) / (float)CROPN - 1.0f;
  float gy = (2.0f * yy + 1.0f) / (float)CROPN - 1.0f;
  float grid_x = th[0]*gx + th[1]*gy + th[2];
  float grid_y = th[3]*gx + th[4]*gy + th[5];
  float ix = ((grid_x + 1.0f) * (float)IMG_W - 1.0f) * 0.5f;
  float iy = ((grid_y + 1.0f) * (float)IMG_H - 1.0f) * 0.5f;
  float x0 = floorf(ix), y0 = floorf(iy);
  float wx = ix - x0, wy = iy - y0;
  int cam = i % NCAM, b = i / (NBOXB * NCAM);
  const float* base = imgs + (size_t)(b * NCAM + cam) * 3 * IMG_H * IMG_W;

  float xf[2] = { x0, x0 + 1.0f };
  float yf[2] = { y0, y0 + 1.0f };
  float wxa[2] = { 1.0f - wx, wx };
  float wya[2] = { 1.0f - wy, wy };
  int   xi[2], yi[2], vx[2], vy[2];
  for (int j = 0; j < 2; j++) {
    vx[j] = (xf[j] >= 0.0f) && (xf[j] <= (float)(IMG_W - 1));
    vy[j] = (yf[j] >= 0.0f) && (yf[j] <= (float)(IMG_H - 1));
    xi[j] = (int)fminf(fmaxf(xf[j], 0.0f), (float)(IMG_W - 1));
    yi[j] = (int)fminf(fmaxf(yf[j], 0.0f), (float)(IMG_H - 1));
  }
  float res[3];
  #pragma unroll
  for (int ch = 0; ch < 3; ch++) {
    const float* cp = base + (size_t)ch * IMG_H * IMG_W;
    float r = 0.0f;
    #pragma unroll
    for (int jy = 0; jy < 2; jy++)
      #pragma unroll
      for (int jx = 0; jx < 2; jx++) {
        float val = (vx[jx] && vy[jy]) ? cp[yi[jy] * IMG_W + xi[jx]] : 0.0f;
        r += val * wxa[jx] * wya[jy];
      }
    res[ch] = r;
  }
  u16x4 st = { f2us(res[0]), f2us(res[1]), f2us(res[2]), 0 };
  *(u16x4*)(crops + ((size_t)i * 228 * 228 + (size_t)(yy + 1) * 228 + (xx + 1)) * 4) = st;
}

// =========================================================================
// MFMA convs. mfma_f32_16x16x32_bf16: A[m=lane&15][k=quad*8+j], B[k][n=lane&15],
// D: col(n)=lane&15, row(m)=quad*4+reg.
// LDS swizzle (64-bank model): 16B-chunk slot = base | ((c ^ g) & 15),
// g = 4-bit key distinct mod 16 across the 16 lanes of an n-tile.
// =========================================================================

// ---------------- conv1: 3->64, 7x7 s4, SAME(pad 1,2) via halo buffer, K=224 ----------------
#define C1_GROUPS 34            // ceil(2166/64) groups of 64 16B-chunks
__global__ __launch_bounds__(256) void k_conv1m(const u16* __restrict__ X, // crops_cl
                                                const u16* __restrict__ W, // W1f [4][28][16][8]
                                                u16* __restrict__ out) {   // [i][3136][64]
  __shared__ u16x8 sX[C1_GROUPS * 64];   // 2176 chunks = 34,816 B
  int blk = blockIdx.x;                  // 384*14
  int i = blk / 14, rg = blk % 14;
  int tid = threadIdx.x, wv = tid >> 6, lane = tid & 63;
  int m = lane & 15, quad = lane >> 4;

  // ---- stage rows rg*16 .. rg*16+18 (2166 16B chunks) ----
  const u16* src = X + ((size_t)i * 51984 + (size_t)(rg * 16) * 228) * 4;
  #pragma unroll
  for (int j = 0; j < 9; j++) {
    int g = wv + j * 4;                  // wave-uniform group id
    if (g < C1_GROUPS) {
      int c = g * 64 + lane;
      int cc = c < 2166 ? c : 2165;      // clamp source; dup lands in LDS pad
      __builtin_amdgcn_global_load_lds(
          (const __attribute__((address_space(1))) void*)(src + (size_t)cc * 8),
          (__attribute__((address_space(3))) void*)(sX + g * 64),
          16, 0, 0);
    }
  }
  __syncthreads();

  int col[4];
  #pragma unroll
  for (int nt = 0; nt < 4; nt++) col[nt] = nt * 16 + m;   // valid < 56
  f32x4 acc[4][4];
  #pragma unroll
  for (int t = 0; t < 4; t++)
    #pragma unroll
    for (int nt = 0; nt < 4; nt++) acc[t][nt] = (f32x4){0.f, 0.f, 0.f, 0.f};

  #pragma unroll
  for (int r = 0; r < 7; r++) {
    bf16x8 a[4];
    #pragma unroll
    for (int t = 0; t < 4; t++)
      a[t] = as_b(*(const u16x8*)(W + (size_t)(((t * 28 + r * 4 + quad) * 16 + m) * 8)));
    int lrow = wv * 4 + r;               // 0..18
    #pragma unroll
    for (int nt = 0; nt < 4; nt++) {
      int cl = col[nt] < 56 ? col[nt] : 55;
      bf16x8 bfr = as_b(sX[lrow * 114 + cl * 2 + quad]);
      #pragma unroll
      for (int t = 0; t < 4; t++)
        acc[t][nt] = __builtin_amdgcn_mfma_f32_16x16x32_bf16(a[t], bfr, acc[t][nt], 0, 0, 0);
    }
  }
  int oh = rg * 4 + wv;
  #pragma unroll
  for (int nt = 0; nt < 4; nt++) {
    if (col[nt] < 56) {
      int n = oh * 56 + col[nt];
      #pragma unroll
      for (int t = 0; t < 4; t++) {
        u16x4 st;
        #pragma unroll
        for (int r4 = 0; r4 < 4; r4++) st[r4] = f2us(fmaxf(acc[t][nt][r4], 0.f));
        *(u16x4*)(out + ((size_t)i * 3136 + n) * 64 + t * 16 + quad * 4) = st;
      }
    }
  }
}

// ---------------- conv2: 64->256, 3x3 s4, pad 0, K=576 ----------------
__global__ __launch_bounds__(256, 3) void k_conv2m(const u16* __restrict__ X, // c1o [i][3136][64]
                                                   const u16* __restrict__ W, // W2f [16][72][16][8]
                                                   u16* __restrict__ out) {   // [i][196][256]
  __shared__ u16x8 s2[3136];           // 50,176 B
  int bid = blockIdx.x;                // 384*7
  int i = bid / 7, ohg = bid % 7;
  int tid = threadIdx.x, wv = tid >> 6, lane = tid & 63;
  int m = lane & 15, quad = lane >> 4;

  // ---- stage: 3136 16B chunks, swizzled reg-staging ----
  const u16* src = X + ((size_t)i * 3136 + 8 * ohg * 56) * 64;
  u16x8 tmp[13];
  #pragma unroll
  for (int j = 0; j < 13; j++) {
    int c = tid + j * 256;
    int cc = c < 3136 ? c : 3135;
    tmp[j] = *(const u16x8*)(src + (size_t)cc * 8);
  }
  #pragma unroll
  for (int j = 0; j < 13; j++) {
    int c = tid + j * 256;
    int cc = c < 3136 ? c : 3135;
    int pixel = cc >> 3;
    int li = pixel / 56, iw = pixel - li * 56;
    int g = (14 * (li >> 2) + (iw >> 2)) & 15;
    s2[(cc & ~15) | ((cc ^ g) & 15)] = tmp[j];
  }
  __syncthreads();

  // ---- per-lane B params: pk2[rk][nt] = base2 | (g&7), slot = (pkv&~7)|(sub^(pkv&7)) ----
  int nl[2], pk2[9][2];
  #pragma unroll
  for (int nt = 0; nt < 2; nt++) {
    int n = nt * 16 + m;
    nl[nt] = n;
    int nc = n < 28 ? n : 27;
    int ohl = nc / 14, ow = nc - ohl * 14;
    int g = nc & 15;
    #pragma unroll
    for (int rk = 0; rk < 9; rk++) {
      int r = rk / 3, kw = rk % 3;
      int pixel = (ohl * 4 + r) * 56 + (ow * 4 + kw);
      int cb = pixel * 8;
      int base2 = (cb & ~15) | ((cb & 8) ^ (g & 8));
      pk2[rk][nt] = base2 | (g & 7);
    }
  }
  f32x4 acc[4][2];
  #pragma unroll
  for (int t = 0; t < 4; t++)
    #pragma unroll
    for (int nt = 0; nt < 2; nt++) acc[t][nt] = (f32x4){0.f, 0.f, 0.f, 0.f};

  const u16* wbase = W + (size_t)(wv * 4) * (72 * 128) + m * 8;
  auto loadA = [&](int t, int s) {
    return as_b(*(const u16x8*)(wbase + (size_t)(t * 72 + s * 4 + quad) * 128));
  };
  auto loadB = [&](int nt, int s) {
    int pkv = pk2[s >> 1][nt];
    int sub = (s & 1) * 4 + quad;
    return as_b(s2[(pkv & ~7) | (sub ^ (pkv & 7))]);
  };

  bf16x8 A_[3][4], B_[3][2];
  #pragma unroll
  for (int t = 0; t < 4; t++) { A_[0][t] = loadA(t, 0); A_[1][t] = loadA(t, 1); }
  #pragma unroll
  for (int nt = 0; nt < 2; nt++) { B_[0][nt] = loadB(nt, 0); B_[1][nt] = loadB(nt, 1); }

  #pragma unroll
  for (int s = 0; s < 18; s++) {
    if (s + 2 < 18) {
      #pragma unroll
      for (int t = 0; t < 4; t++) A_[(s + 2) % 3][t] = loadA(t, s + 2);
      #pragma unroll
      for (int nt = 0; nt < 2; nt++) B_[(s + 2) % 3][nt] = loadB(nt, s + 2);
    }
    #pragma unroll
    for (int nt = 0; nt < 2; nt++)
      #pragma unroll
      for (int t = 0; t < 4; t++)
        acc[t][nt] = __builtin_amdgcn_mfma_f32_16x16x32_bf16(A_[s % 3][t], B_[s % 3][nt], acc[t][nt], 0, 0, 0);
  }

  #pragma unroll
  for (int nt = 0; nt < 2; nt++) {
    if (nl[nt] < 28) {
      int n = ohg * 28 + nl[nt];
      #pragma unroll
      for (int t = 0; t < 4; t++) {
        u16x4 st;
        #pragma unroll
        for (int r4 = 0; r4 < 4; r4++) st[r4] = f2us(fmaxf(acc[t][nt][r4], 0.f));
        *(u16x4*)(out + ((size_t)i * 196 + n) * 256 + wv * 64 + t * 16 + quad * 4) = st;
      }
    }
  }
}

// ---------------- conv3: 256->1024, 3x3 s2, pad after=1, K=2304 -> (i,p,oc) f32 ----------------
// v8: occupancy via register cut. r8 showed the binder is TOTAL regs (124 arch +
//     64 AGPR = 188 > 170 -> 2 waves/SIMD, LDS irrelevant). v8: 256-thread
//     blocks (1-wave/SIMD granularity), grid = 384 img x 4 oc-quarters = 1536,
//     launch_bounds(256,3). dist-1 A (A_[2], -16 regs), packed B-params,
//     wave-uniform-base + fixed-lane-offset A addressing (SGPR saddr form).
//     Target <=104 arch + 64 acc -> 3 waves/SIMD. Same h-loop staging as r8.
__global__ __launch_bounds__(256, 3) void k_conv3m(const u16* __restrict__ X, // c2o [i][196][256]
                                                   const u16* __restrict__ W, // W3f frag layout
                                                   float* __restrict__ out3) {
  __shared__ u16x8 sX8[3152];          // 196x16 chunks + zero row @3136; 50,432 B
  int bid = blockIdx.x;                // 1536
  int og = (bid >> 1) & 3;             // XCD pair per og quarter (1.18MB L2-resident)
  int i  = (bid >> 3) * 2 + (bid & 1); // bijective over 384
  int tid = threadIdx.x;
  int wv = tid >> 6, lane = tid & 63;  // 4 waves

  const u16* src = X + (size_t)i * 50176;   // u16 units; 6272 16B-chunks total

  // stage half h: 3136 chunks (49 groups of 64), pre-swizzled source -> linear LDS
  auto stage = [&](int h) {
    #pragma unroll
    for (int j = 0; j < 13; j++) {
      int gi = wv + j * 4;               // wave-uniform, 0..51
      if (gi < 49) {
        int slot = gi * 64 + lane;       // 0..3135
        int p = slot >> 4, cq = slot & 15;
        int ih = p / 14, iw = p - ih * 14;
        int g = (7 * (ih >> 1) + (iw >> 1)) & 15;
        int gc = p * 32 + h * 16 + (cq ^ g);
        __builtin_amdgcn_global_load_lds(
            (const __attribute__((address_space(1))) void*)(src + (size_t)gc * 8),
            (__attribute__((address_space(3))) void*)(sX8 + gi * 64),
            16, 0, 0);
      }
    }
  };

  stage(0);
  if (tid < 16) sX8[3136 + tid] = (u16x8){0,0,0,0,0,0,0,0};  // zero row (once)

  int m = lane & 15, quad = lane >> 4;
  int ocw = og * 256 + wv * 64;
  int narr[4], oh2[4], ow2[4];
  #pragma unroll
  for (int nt = 0; nt < 4; nt++) {
    int n = nt * 16 + m;
    narr[nt] = n;
    int nc = n < 49 ? n : 48;
    int oh = nc / 7, ow = nc - oh * 7;
    oh2[nt] = oh * 2; ow2[nt] = ow * 2;
  }
  f32x4 acc[4][4];
  #pragma unroll
  for (int t = 0; t < 4; t++)
    #pragma unroll
    for (int nt = 0; nt < 4; nt++) acc[t][nt] = (f32x4){0.f, 0.f, 0.f, 0.f};

  // wave-uniform weight base (SGPR) + fixed per-lane offset (VGPR)
  const u16* wuni = W + (size_t)(ocw >> 4) * (288 * 128);
  const int laneA = quad * 128 + m * 8;

  int pk[4];   // packed B params: (chunk_base << 4) | g
  auto set_bparams = [&](int rk) {
    const int r = rk / 3, kw = rk % 3;
    #pragma unroll
    for (int nt = 0; nt < 4; nt++) {
      int ih = oh2[nt] + r, iw = ow2[nt] + kw;
      bool valid = (narr[nt] < 49) && (ih < 14) && (iw < 14);
      int p = ih * 14 + iw;
      int g = (7 * (ih >> 1) + (iw >> 1)) & 15;
      pk[nt] = valid ? (((p * 16) << 4) | g) : (3136 << 4);
    }
  };
  // half h, step s in [0,36): rk = s>>2; kblk = rk*32 + h*16 + (s&3)*4 + quad
  // A addr (u16) = wuni + t*36864 + [(s>>2)*4096 + h*2048 + (s&3)*512] + laneA
  auto loadA = [&](int t, int s, int h) {
    int uo = t * 36864 + (s >> 2) * 4096 + h * 2048 + (s & 3) * 512;  // compile-time
    return as_b(*(const u16x8*)(wuni + uo + laneA));
  };
  auto loadB = [&](int nt, int s) {
    int q = (s & 3) * 4 + quad;          // within-half chunk [0,16)
    return as_b(sX8[(pk[nt] >> 4) + (q ^ (pk[nt] & 15))]);
  };

  bf16x8 A_[2][4], B_[2][4];

  #pragma unroll
  for (int h = 0; h < 2; h++) {
    __syncthreads();                     // stage(h) data landed (barrier drains DMA)
    set_bparams(0);
    #pragma unroll
    for (int t = 0; t < 4; t++) A_[0][t] = loadA(t, 0, h);
    #pragma unroll
    for (int nt = 0; nt < 4; nt++) B_[0][nt] = loadB(nt, 0);

    #pragma unroll
    for (int s = 0; s < 36; s++) {
      if (s + 1 < 36) {
        if (((s + 1) & 3) == 0) set_bparams((s + 1) >> 2);
        #pragma unroll
        for (int t = 0; t < 4; t++) A_[(s + 1) & 1][t] = loadA(t, s + 1, h);
        #pragma unroll
        for (int nt = 0; nt < 4; nt++) B_[(s + 1) & 1][nt] = loadB(nt, s + 1);
      }
      #pragma unroll
      for (int nt = 0; nt < 4; nt++)
        #pragma unroll
        for (int t = 0; t < 4; t++)
          acc[t][nt] = __builtin_amdgcn_mfma_f32_16x16x32_bf16(A_[s & 1][t], B_[s & 1][nt], acc[t][nt], 0, 0, 0);
    }
    if (h == 0) {
      __syncthreads();                   // all waves done reading half 0
      stage(1);                          // restage; next-loop barrier drains
    }
  }

  #pragma unroll
  for (int nt = 0; nt < 4; nt++) {
    int n = narr[nt];
    if (n < 49) {
      #pragma unroll
      for (int t = 0; t < 4; t++) {
        f32x4 o;
        #pragma unroll
        for (int r4 = 0; r4 < 4; r4++) o[r4] = fmaxf(acc[t][nt][r4], 0.f);
        *(f32x4*)(out3 + ((size_t)i * 49 + n) * DIMN + ocw + t * 16 + quad * 4) = o;
      }
    }
  }
}

// ---------------- tokens: mean + concat + pos ----------------
__global__ __launch_bounds__(256) void k_tok(const float* __restrict__ h,   // (384,49,1024)
                                             const float* __restrict__ pos, // (50,1024)
                                             float* __restrict__ tok) {     // (384,50,1024)
  int blk = blockIdx.x;               // 384*50
  int i = blk / 50, t = blk % 50;
  int d = threadIdx.x * 4;
  float4 val;
  if (t == 0) {
    float sx = 0, sy = 0, sz = 0, sw = 0;
    for (int p = 0; p < 49; p++) {
      float4 v = *(const float4*)(h + ((size_t)i * 49 + p) * DIMN + d);
      sx += v.x; sy += v.y; sz += v.z; sw += v.w;
    }
    const float inv49 = 1.0f / 49.0f;
    val.x = sx * inv49; val.y = sy * inv49; val.z = sz * inv49; val.w = sw * inv49;
  } else {
    val = *(const float4*)(h + ((size_t)i * 49 + (t - 1)) * DIMN + d);
  }
  float4 pe = *(const float4*)(pos + (size_t)t * DIMN + d);
  float4 o; o.x = val.x + pe.x; o.y = val.y + pe.y; o.z = val.z + pe.z; o.w = val.w + pe.w;
  *(float4*)(tok + ((size_t)i * 50 + t) * DIMN + d) = o;
}

// ---------------- batched matvec: out[i,:] = vec[i,:] @ M, 4 images x 512 cols / block ----------------
__global__ __launch_bounds__(256) void k_matvec2(const float* __restrict__ vecs, int vstride,
                                                 const float* __restrict__ M,
                                                 float* __restrict__ out) {
  __shared__ float s_v[4][DIMN];
  int i0 = blockIdx.x * 4;
  int h = blockIdx.y;
  for (int e = threadIdx.x; e < 4 * DIMN; e += 256)
    s_v[e >> 10][e & 1023] = vecs[(size_t)(i0 + (e >> 10)) * vstride + (e & 1023)];
  __syncthreads();
  int d0 = h * 512 + threadIdx.x * 2;
  float2 acc[4] = {{0,0},{0,0},{0,0},{0,0}};
  for (int e = 0; e < DIMN; e++) {
    float2 w = *(const float2*)(M + (size_t)e * DIMN + d0);
    #pragma unroll
    for (int im = 0; im < 4; im++) {
      float x = s_v[im][e];
      acc[im].x += x * w.x; acc[im].y += x * w.y;
    }
  }
  #pragma unroll
  for (int im = 0; im < 4; im++)
    *(float2*)(out + (size_t)(i0 + im) * DIMN + d0) = acc[im];
}

// ---------------- scores + softmax + attn-weighted token mix ----------------
__global__ __launch_bounds__(256) void k_attn(const float* __restrict__ tok,
                                              const float* __restrict__ a1,
                                              float* __restrict__ tvec) {
  __shared__ float s_a[DIMN];
  __shared__ float s_sc[50];
  __shared__ float s_at[50];
  int i = blockIdx.x;
  for (int e = threadIdx.x; e < DIMN; e += 256) s_a[e] = a1[(size_t)i * DIMN + e];
  __syncthreads();
  int wave = threadIdx.x >> 6, lane = threadIdx.x & 63;
  for (int t = wave; t < 50; t += 4) {
    const float* tr = tok + ((size_t)i * 50 + t) * DIMN;
    float p = 0.0f;
    for (int mm = 0; mm < 16; mm++) {
      int e = lane + mm * 64;
      p += tr[e] * s_a[e];
    }
    for (int off = 32; off > 0; off >>= 1) p += __shfl_down(p, off, 64);
    if (lane == 0) s_sc[t] = p * 0.03125f;  // DIM^-0.5
  }
  __syncthreads();
  if (threadIdx.x == 0) {
    float mx = s_sc[0];
    for (int t = 1; t < 50; t++) mx = fmaxf(mx, s_sc[t]);
    float sum = 0.0f;
    for (int t = 0; t < 50; t++) { float ex = expf(s_sc[t] - mx); s_at[t] = ex; sum += ex; }
    float inv = 1.0f / sum;
    for (int t = 0; t < 50; t++) s_at[t] *= inv;
  }
  __syncthreads();
  int d0 = threadIdx.x * 4;
  float ax = 0, ay = 0, az = 0, aw = 0;
  for (int t = 0; t < 50; t++) {
    float at = s_at[t];
    float4 tv = *(const float4*)(tok + ((size_t)i * 50 + t) * DIMN + d0);
    ax += at * tv.x; ay += at * tv.y; az += at * tv.z; aw += at * tv.w;
  }
  float4 o; o.x = ax; o.y = ay; o.z = az; o.w = aw;
  *(float4*)(tvec + (size_t)i * DIMN + d0) = o;
}

// ---------------- final momentum merge ----------------
__global__ void k_final(const float* __restrict__ emb,
                        const int* __restrict__ valid,
                        const float* __restrict__ bdd,
                        const float* __restrict__ momp,
                        float* __restrict__ out) {
  int n = blockIdx.x;
  int d0 = threadIdx.x * 4;
  float mom = momp[0];
  float e[4];
  #pragma unroll
  for (int j = 0; j < 4; j++) e[j] = bdd[d0 + j];
  const int order[6] = {2, 0, 1, 5, 3, 4};
  #pragma unroll
  for (int s = 0; s < 6; s++) {
    int c = order[s];
    int i = n * NCAM + c;
    if (valid[i]) {
      const float* er = emb + (size_t)i * DIMN + d0;
      #pragma unroll
      for (int j = 0; j < 4; j++) e[j] = mom * e[j] + (1.0f - mom) * er[j];
    }
  }
  #pragma unroll
  for (int j = 0; j < 4; j++) out[(size_t)n * DIMN + d0 + j] = e[j];
}

extern "C" void kernel_launch(void* const* d_in, const int* in_sizes, int n_in,
                              void* d_out, int out_size, void* d_ws, size_t ws_size,
                              hipStream_t stream) {
  const float* in_cam = (const float*)d_in[0];
  const float* in_box = (const float*)d_in[1];
  const float* in_aug = (const float*)d_in[2];
  const float* in_la  = (const float*)d_in[3];
  const float* in_l2i = (const float*)d_in[4];
  const float* in_mom = (const float*)d_in[5];
  const float* in_bdd = (const float*)d_in[6];
  const float* in_tw  = (const float*)d_in[7];
  const float* in_tb  = (const float*)d_in[8];
  const float* in_c1  = (const float*)d_in[9];
  const float* in_c2  = (const float*)d_in[10];
  const float* in_c3  = (const float*)d_in[11];
  const float* in_pe  = (const float*)d_in[12];
  const float* in_wq  = (const float*)d_in[13];
  const float* in_wk  = (const float*)d_in[14];
  const float* in_wv  = (const float*)d_in[15];
  const float* in_wo  = (const float*)d_in[16];

  char* base = (char*)d_ws;
  size_t off = 0;
  auto carve = [&](size_t bytes) -> char* {
    char* p = base + off;
    off += (bytes + 255) & ~(size_t)255;
    return p;
  };
  float* theta   = (float*)carve((size_t)NIMG * 6 * 4);
  int*   valid   = (int*)carve((size_t)NIMG * 4);
  float* qbuf    = (float*)carve((size_t)NIMG * DIMN * 4);
  float* a1buf   = (float*)carve((size_t)NIMG * DIMN * 4);
  float* tvbuf   = (float*)carve((size_t)NIMG * DIMN * 4);
  float* ctxbuf  = (float*)carve((size_t)NIMG * DIMN * 4);
  float* embbuf  = (float*)carve((size_t)NIMG * DIMN * 4);
  float* wkT_f   = (float*)carve((size_t)DIMN * DIMN * 4);
  u16*   W1r     = (u16*)carve((size_t)64 * 224 * 2);
  u16*   W2r     = (u16*)carve((size_t)256 * 576 * 2);
  u16*   W3r     = (u16*)carve((size_t)1024 * 2304 * 2);
  u16*   c2o     = (u16*)carve((size_t)NIMG * 196 * 256 * 2);
  char*  R1      = carve((size_t)NIMG * 228 * 228 * 4 * 2);   // crops_cl / (conv3o + tok)
  u16*   c1o     = (u16*)carve((size_t)NIMG * 3136 * 64 * 2);
  u16*   crops   = (u16*)R1;
  float* conv3o  = (float*)R1;
  float* tok     = (float*)(R1 + (size_t)NIMG * 49 * DIMN * 4);

  k_w1r<<<56, 256, 0, stream>>>(in_c1, W1r);
  k_w2r<<<576, 256, 0, stream>>>(in_c2, W2r);
  k_w3r<<<9216, 256, 0, stream>>>(in_c3, W3r);
  k_transpose_t<<<dim3(32, 32), dim3(32, 8), 0, stream>>>(in_wk, wkT_f);

  k_proj<<<1, 384, 0, stream>>>(in_box, in_la, in_l2i, in_aug, in_tw, in_tb, theta, valid);
  k_zero_halo<<<(NIMG * HALO_PX + 255) / 256, 256, 0, stream>>>((u16x4*)crops);
  k_sample<<<(NIMG * CROPN * CROPN) / 256, 256, 0, stream>>>(in_cam, theta, crops);
  k_conv1m<<<NIMG * 14, 256, 0, stream>>>(crops, W1r, c1o);
  k_conv2m<<<NIMG * 7, 256, 0, stream>>>(c1o, W2r, c2o);
  k_conv3m<<<1536, 256, 0, stream>>>(c2o, W3r, conv3o);
  k_tok<<<NIMG * 50, 256, 0, stream>>>(conv3o, in_pe, tok);
  k_matvec2<<<dim3(96, 2), 256, 0, stream>>>(tok, 50 * DIMN, in_wq, qbuf);
  k_matvec2<<<dim3(96, 2), 256, 0, stream>>>(qbuf, DIMN, wkT_f, a1buf);
  k_attn<<<NIMG, 256, 0, stream>>>(tok, a1buf, tvbuf);
  k_matvec2<<<dim3(96, 2), 256, 0, stream>>>(tvbuf, DIMN, in_wv, ctxbuf);
  k_matvec2<<<dim3(96, 2), 256, 0, stream>>>(ctxbuf, DIMN, in_wo, embbuf);
  k_final<<<NBOX, 256, 0, stream>>>(embbuf, valid, in_bdd, in_mom, (float*)d_out);
}

// Round 11
// 903.712 us; speedup vs baseline: 1.1195x; 1.1195x over previous
//
#include <hip/hip_runtime.h>
#include <hip/hip_bf16.h>

#define DIMN 1024
#define IMG_H 512
#define IMG_W 1408
#define CROPN 224
#define NCAM 6
#define NBOXB 32
#define NBOX 64            // NBATCH*NBOXB
#define NIMG 384           // NBOX*NCAM

typedef __hip_bfloat16 bf16;
typedef unsigned short u16;
typedef float f32x4 __attribute__((ext_vector_type(4)));
typedef short bf16x8 __attribute__((ext_vector_type(8)));
typedef u16 u16x4 __attribute__((ext_vector_type(4)));
typedef u16 u16x8 __attribute__((ext_vector_type(8)));

__device__ __forceinline__ float b2f(bf16 x) { return __bfloat162float(x); }
__device__ __forceinline__ u16 f2us(float x) {
  bf16 h = __float2bfloat16(x);
  return *(u16*)&h;
}
__device__ __forceinline__ bf16x8 as_b(u16x8 x) {
  union { u16x8 u; bf16x8 b; } c; c.u = x; return c.b;
}

// ---------------- prep: weight reorders (K-order = (r,kw),ic  channel-last) ----------------
// conv1 (64,3,7,7) -> fragment-contiguous W1f[ocb=oc>>4][kb=K>>3][m=oc&15][kj=K&7]
// K = r*32 + kw*4 + ch (kw<7, ch<3 else 0). A-frag load = 1KB contiguous per wave.
__global__ void k_w1r(const float* __restrict__ in, u16* __restrict__ out) {
  int idx = blockIdx.x * 256 + threadIdx.x;
  if (idx >= 64 * 224) return;
  int oc = idx / 224, t = idx % 224;
  int r = t >> 5, u = t & 31, kw = u >> 2, ch = u & 3;
  u16 v = (kw < 7 && ch < 3) ? f2us(in[((oc * 3 + ch) * 7 + r) * 7 + kw]) : (u16)0;
  out[(((oc >> 4) * 28 + (t >> 3)) * 16 + (oc & 15)) * 8 + (t & 7)] = v;
}
// conv2 (256,64,3,3) -> fragment-contiguous W2f[ocb=oc>>4][kb=K>>3][m=oc&15][kj=K&7]
// K = (r*3+kw)*64 + ic
__global__ void k_w2r(const float* __restrict__ in, u16* __restrict__ out) {
  int idx = blockIdx.x * 256 + threadIdx.x;
  if (idx >= 256 * 576) return;
  int oc = idx / 576, t = idx % 576;
  int rk = t >> 6, ic = t & 63, r = rk / 3, kw = rk % 3;
  u16 v = f2us(in[((oc * 64 + ic) * 3 + r) * 3 + kw]);
  out[(((oc >> 4) * 72 + (t >> 3)) * 16 + (oc & 15)) * 8 + (t & 7)] = v;
}
// conv3 (1024,256,3,3) -> fragment-contiguous layout:
// W3f[ocblk=oc>>4][kblk=K>>3][m=oc&15][kj=K&7], K = (r*3+kw)*256 + ic
__global__ void k_w3r(const float* __restrict__ in, u16* __restrict__ out) {
  int idx = blockIdx.x * 256 + threadIdx.x;
  if (idx >= 1024 * 2304) return;
  int oc = idx / 2304, t = idx % 2304;
  int rk = t >> 8, ic = t & 255, r = rk / 3, kw = rk % 3;
  u16 v = f2us(in[((oc * 256 + ic) * 3 + r) * 3 + kw]);
  int ocb = oc >> 4, mm = oc & 15, kb = t >> 3, kj = t & 7;
  out[(((size_t)ocb * 288 + kb) * 16 + mm) * 8 + kj] = v;
}
// tiled transpose 1024x1024 f32 (wk -> wkT)
__global__ void k_transpose_t(const float* __restrict__ w, float* __restrict__ wt) {
  __shared__ float tile[32][33];
  int x = blockIdx.x * 32 + threadIdx.x;
  for (int j = threadIdx.y; j < 32; j += 8)
    tile[j][threadIdx.x] = w[(size_t)(blockIdx.y * 32 + j) * 1024 + x];
  __syncthreads();
  int x2 = blockIdx.y * 32 + threadIdx.x;
  for (int j = threadIdx.y; j < 32; j += 8)
    wt[(size_t)(blockIdx.x * 32 + j) * 1024 + x2] = tile[threadIdx.x][j];
}

// ---------------- projection + theta ----------------
__global__ void k_proj(const float* __restrict__ boxes, const float* __restrict__ la_m,
                       const float* __restrict__ l2i, const float* __restrict__ aug,
                       const float* __restrict__ tw, const float* __restrict__ tb,
                       float* __restrict__ theta_out, int* __restrict__ valid_out) {
  int t = threadIdx.x;
  if (t >= NIMG) return;
  int n = t / NCAM, cam = t % NCAM;
  int b = n / NBOXB, nb = n % NBOXB;

  float la[4][4];
  for (int r = 0; r < 4; r++)
    for (int c = 0; c < 4; c++) la[r][c] = la_m[b * 16 + r * 4 + c];
  float a00=la[0][0],a01=la[0][1],a02=la[0][2];
  float a10=la[1][0],a11=la[1][1],a12=la[1][2];
  float a20=la[2][0],a21=la[2][1],a22=la[2][2];
  float c00 =  a11*a22 - a12*a21;
  float c01 = -(a10*a22 - a12*a20);
  float c02 =  a10*a21 - a11*a20;
  float det = a00*c00 + a01*c01 + a02*c02;
  float id = 1.0f / det;
  float inv[3][3];
  inv[0][0] = c00*id;                 inv[0][1] = -(a01*a22-a02*a21)*id;  inv[0][2] =  (a01*a12-a02*a11)*id;
  inv[1][0] = c01*id;                 inv[1][1] =  (a00*a22-a02*a20)*id;  inv[1][2] = -(a00*a12-a02*a10)*id;
  inv[2][0] = c02*id;                 inv[2][1] = -(a00*a21-a01*a20)*id;  inv[2][2] =  (a00*a11-a01*a10)*id;

  float bx[9];
  for (int i = 0; i < 9; i++) bx[i] = boxes[(b * NBOXB + nb) * 9 + i];
  float c0[3] = { bx[0]-la[0][3], bx[1]-la[1][3], bx[2]-la[2][3] };
  float c1[3];
  for (int r = 0; r < 3; r++) c1[r] = inv[r][0]*c0[0] + inv[r][1]*c0[1] + inv[r][2]*c0[2];

  const float* M = l2i + (size_t)(b * NCAM + cam) * 16;
  float p[3];
  for (int r = 0; r < 3; r++)
    p[r] = M[r*4+0]*c1[0] + M[r*4+1]*c1[1] + M[r*4+2]*c1[2] + M[r*4+3];
  float z = fminf(fmaxf(p[2], 1e-5f), 100000.0f);
  float x = p[0] / z, y = p[1] / z;
  const float* A = aug + (size_t)(b * NCAM + cam) * 16;
  float u = A[0]*x + A[1]*y + A[2]*z + A[3];
  float v = A[4]*x + A[5]*y + A[6]*z + A[7];

  int on = (v < (float)IMG_H) && (v >= 0.0f) && (u < (float)IMG_W) && (u >= 0.0f);
  float ty = v / (float)IMG_H * 2.0f - 1.0f;
  float tx = u / (float)IMG_W * 2.0f - 1.0f;

  float s[4];
  for (int j = 0; j < 4; j++) {
    float acc = tb[j];
    for (int i = 0; i < 9; i++) acc += tw[j * 9 + i] * bx[i];
    s[j] = tanhf(acc);
  }
  float* o = theta_out + t * 6;
  o[0] = s[0]; o[1] = s[1]; o[2] = tx;
  o[3] = s[2]; o[4] = s[3]; o[5] = ty;
  valid_out[t] = on;
}

// ---------------- zero the crop halo (rows/cols 0,225,226 of 228x228 ch-last buffer) ----------------
#define HALO_PX 1356   // 3*228 + 224*3
__global__ void k_zero_halo(u16x4* __restrict__ c) {
  int t = blockIdx.x * 256 + threadIdx.x;
  int i = t / HALO_PX;
  if (i >= NIMG) return;
  int r = t % HALO_PX;
  int ph, pw;
  if (r < 684) {
    int rr = r / 228;
    ph = (rr == 0) ? 0 : (rr == 1 ? 225 : 226);
    pw = r % 228;
  } else {
    int q = r - 684;
    ph = 1 + q / 3;
    int s = q % 3;
    pw = (s == 0) ? 0 : (s == 1 ? 225 : 226);
  }
  c[(size_t)i * 228 * 228 + ph * 228 + pw] = (u16x4){0, 0, 0, 0};
}

// ---------------- crop sampling -> channel-last halo'd crops [i][228][228][4] bf16 ----------------
__global__ __launch_bounds__(256) void k_sample(const float* __restrict__ imgs,
                                                const float* __restrict__ theta,
                                                u16* __restrict__ crops) {
  int idx = blockIdx.x * 256 + threadIdx.x;   // NIMG*224*224 exactly
  int i = idx / (CROPN * CROPN);
  int rem = idx - i * (CROPN * CROPN);
  int yy = rem / CROPN, xx = rem % CROPN;
  const float* th = theta + i * 6;
  float gx = (2.0f * xx + 1.0f) / (float)CROPN - 1.0f;
  float gy = (2.0f * yy + 1.0f) / (float)CROPN - 1.0f;
  float grid_x = th[0]*gx + th[1]*gy + th[2];
  float grid_y = th[3]*gx + th[4]*gy + th[5];
  float ix = ((grid_x + 1.0f) * (float)IMG_W - 1.0f) * 0.5f;
  float iy = ((grid_y + 1.0f) * (float)IMG_H - 1.0f) * 0.5f;
  float x0 = floorf(ix), y0 = floorf(iy);
  float wx = ix - x0, wy = iy - y0;
  int cam = i % NCAM, b = i / (NBOXB * NCAM);
  const float* base = imgs + (size_t)(b * NCAM + cam) * 3 * IMG_H * IMG_W;

  float xf[2] = { x0, x0 + 1.0f };
  float yf[2] = { y0, y0 + 1.0f };
  float wxa[2] = { 1.0f - wx, wx };
  float wya[2] = { 1.0f - wy, wy };
  int   xi[2], yi[2], vx[2], vy[2];
  for (int j = 0; j < 2; j++) {
    vx[j] = (xf[j] >= 0.0f) && (xf[j] <= (float)(IMG_W - 1));
    vy[j] = (yf[j] >= 0.0f) && (yf[j] <= (float)(IMG_H - 1));
    xi[j] = (int)fminf(fmaxf(xf[j], 0.0f), (float)(IMG_W - 1));
    yi[j] = (int)fminf(fmaxf(yf[j], 0.0f), (float)(IMG_H - 1));
  }
  float res[3];
  #pragma unroll
  for (int ch = 0; ch < 3; ch++) {
    const float* cp = base + (size_t)ch * IMG_H * IMG_W;
    float r = 0.0f;
    #pragma unroll
    for (int jy = 0; jy < 2; jy++)
      #pragma unroll
      for (int jx = 0; jx < 2; jx++) {
        float val = (vx[jx] && vy[jy]) ? cp[yi[jy] * IMG_W + xi[jx]] : 0.0f;
        r += val * wxa[jx] * wya[jy];
      }
    res[ch] = r;
  }
  u16x4 st = { f2us(res[0]), f2us(res[1]), f2us(res[2]), 0 };
  *(u16x4*)(crops + ((size_t)i * 228 * 228 + (size_t)(yy + 1) * 228 + (xx + 1)) * 4) = st;
}

// =========================================================================
// MFMA convs. mfma_f32_16x16x32_bf16: A[m=lane&15][k=quad*8+j], B[k][n=lane&15],
// D: col(n)=lane&15, row(m)=quad*4+reg.
// LDS swizzle (64-bank model): 16B-chunk slot = base | ((c ^ g) & 15),
// g = 4-bit key distinct mod 16 across the 16 lanes of an n-tile.
// =========================================================================

// ---------------- conv1: 3->64, 7x7 s4, SAME(pad 1,2) via halo buffer, K=224 ----------------
#define C1_GROUPS 34            // ceil(2166/64) groups of 64 16B-chunks
__global__ __launch_bounds__(256) void k_conv1m(const u16* __restrict__ X, // crops_cl
                                                const u16* __restrict__ W, // W1f [4][28][16][8]
                                                u16* __restrict__ out) {   // [i][3136][64]
  __shared__ u16x8 sX[C1_GROUPS * 64];   // 2176 chunks = 34,816 B
  int blk = blockIdx.x;                  // 384*14
  int i = blk / 14, rg = blk % 14;
  int tid = threadIdx.x, wv = tid >> 6, lane = tid & 63;
  int m = lane & 15, quad = lane >> 4;

  // ---- stage rows rg*16 .. rg*16+18 (2166 16B chunks) ----
  const u16* src = X + ((size_t)i * 51984 + (size_t)(rg * 16) * 228) * 4;
  #pragma unroll
  for (int j = 0; j < 9; j++) {
    int g = wv + j * 4;                  // wave-uniform group id
    if (g < C1_GROUPS) {
      int c = g * 64 + lane;
      int cc = c < 2166 ? c : 2165;      // clamp source; dup lands in LDS pad
      __builtin_amdgcn_global_load_lds(
          (const __attribute__((address_space(1))) void*)(src + (size_t)cc * 8),
          (__attribute__((address_space(3))) void*)(sX + g * 64),
          16, 0, 0);
    }
  }
  __syncthreads();

  int col[4];
  #pragma unroll
  for (int nt = 0; nt < 4; nt++) col[nt] = nt * 16 + m;   // valid < 56
  f32x4 acc[4][4];
  #pragma unroll
  for (int t = 0; t < 4; t++)
    #pragma unroll
    for (int nt = 0; nt < 4; nt++) acc[t][nt] = (f32x4){0.f, 0.f, 0.f, 0.f};

  #pragma unroll
  for (int r = 0; r < 7; r++) {
    bf16x8 a[4];
    #pragma unroll
    for (int t = 0; t < 4; t++)
      a[t] = as_b(*(const u16x8*)(W + (size_t)(((t * 28 + r * 4 + quad) * 16 + m) * 8)));
    int lrow = wv * 4 + r;               // 0..18
    #pragma unroll
    for (int nt = 0; nt < 4; nt++) {
      int cl = col[nt] < 56 ? col[nt] : 55;
      bf16x8 bfr = as_b(sX[lrow * 114 + cl * 2 + quad]);
      #pragma unroll
      for (int t = 0; t < 4; t++)
        acc[t][nt] = __builtin_amdgcn_mfma_f32_16x16x32_bf16(a[t], bfr, acc[t][nt], 0, 0, 0);
    }
  }
  int oh = rg * 4 + wv;
  #pragma unroll
  for (int nt = 0; nt < 4; nt++) {
    if (col[nt] < 56) {
      int n = oh * 56 + col[nt];
      #pragma unroll
      for (int t = 0; t < 4; t++) {
        u16x4 st;
        #pragma unroll
        for (int r4 = 0; r4 < 4; r4++) st[r4] = f2us(fmaxf(acc[t][nt][r4], 0.f));
        *(u16x4*)(out + ((size_t)i * 3136 + n) * 64 + t * 16 + quad * 4) = st;
      }
    }
  }
}

// ---------------- conv2: 64->256, 3x3 s4, pad 0, K=576 ----------------
__global__ __launch_bounds__(256, 3) void k_conv2m(const u16* __restrict__ X, // c1o [i][3136][64]
                                                   const u16* __restrict__ W, // W2f [16][72][16][8]
                                                   u16* __restrict__ out) {   // [i][196][256]
  __shared__ u16x8 s2[3136];           // 50,176 B
  int bid = blockIdx.x;                // 384*7
  int i = bid / 7, ohg = bid % 7;
  int tid = threadIdx.x, wv = tid >> 6, lane = tid & 63;
  int m = lane & 15, quad = lane >> 4;

  // ---- stage: 3136 16B chunks, swizzled reg-staging ----
  const u16* src = X + ((size_t)i * 3136 + 8 * ohg * 56) * 64;
  u16x8 tmp[13];
  #pragma unroll
  for (int j = 0; j < 13; j++) {
    int c = tid + j * 256;
    int cc = c < 3136 ? c : 3135;
    tmp[j] = *(const u16x8*)(src + (size_t)cc * 8);
  }
  #pragma unroll
  for (int j = 0; j < 13; j++) {
    int c = tid + j * 256;
    int cc = c < 3136 ? c : 3135;
    int pixel = cc >> 3;
    int li = pixel / 56, iw = pixel - li * 56;
    int g = (14 * (li >> 2) + (iw >> 2)) & 15;
    s2[(cc & ~15) | ((cc ^ g) & 15)] = tmp[j];
  }
  __syncthreads();

  // ---- per-lane B params: pk2[rk][nt] = base2 | (g&7), slot = (pkv&~7)|(sub^(pkv&7)) ----
  int nl[2], pk2[9][2];
  #pragma unroll
  for (int nt = 0; nt < 2; nt++) {
    int n = nt * 16 + m;
    nl[nt] = n;
    int nc = n < 28 ? n : 27;
    int ohl = nc / 14, ow = nc - ohl * 14;
    int g = nc & 15;
    #pragma unroll
    for (int rk = 0; rk < 9; rk++) {
      int r = rk / 3, kw = rk % 3;
      int pixel = (ohl * 4 + r) * 56 + (ow * 4 + kw);
      int cb = pixel * 8;
      int base2 = (cb & ~15) | ((cb & 8) ^ (g & 8));
      pk2[rk][nt] = base2 | (g & 7);
    }
  }
  f32x4 acc[4][2];
  #pragma unroll
  for (int t = 0; t < 4; t++)
    #pragma unroll
    for (int nt = 0; nt < 2; nt++) acc[t][nt] = (f32x4){0.f, 0.f, 0.f, 0.f};

  const u16* wbase = W + (size_t)(wv * 4) * (72 * 128) + m * 8;
  auto loadA = [&](int t, int s) {
    return as_b(*(const u16x8*)(wbase + (size_t)(t * 72 + s * 4 + quad) * 128));
  };
  auto loadB = [&](int nt, int s) {
    int pkv = pk2[s >> 1][nt];
    int sub = (s & 1) * 4 + quad;
    return as_b(s2[(pkv & ~7) | (sub ^ (pkv & 7))]);
  };

  bf16x8 A_[3][4], B_[3][2];
  #pragma unroll
  for (int t = 0; t < 4; t++) { A_[0][t] = loadA(t, 0); A_[1][t] = loadA(t, 1); }
  #pragma unroll
  for (int nt = 0; nt < 2; nt++) { B_[0][nt] = loadB(nt, 0); B_[1][nt] = loadB(nt, 1); }

  #pragma unroll
  for (int s = 0; s < 18; s++) {
    if (s + 2 < 18) {
      #pragma unroll
      for (int t = 0; t < 4; t++) A_[(s + 2) % 3][t] = loadA(t, s + 2);
      #pragma unroll
      for (int nt = 0; nt < 2; nt++) B_[(s + 2) % 3][nt] = loadB(nt, s + 2);
    }
    #pragma unroll
    for (int nt = 0; nt < 2; nt++)
      #pragma unroll
      for (int t = 0; t < 4; t++)
        acc[t][nt] = __builtin_amdgcn_mfma_f32_16x16x32_bf16(A_[s % 3][t], B_[s % 3][nt], acc[t][nt], 0, 0, 0);
  }

  #pragma unroll
  for (int nt = 0; nt < 2; nt++) {
    if (nl[nt] < 28) {
      int n = ohg * 28 + nl[nt];
      #pragma unroll
      for (int t = 0; t < 4; t++) {
        u16x4 st;
        #pragma unroll
        for (int r4 = 0; r4 < 4; r4++) st[r4] = f2us(fmaxf(acc[t][nt][r4], 0.f));
        *(u16x4*)(out + ((size_t)i * 196 + n) * 256 + wv * 64 + t * 16 + quad * 4) = st;
      }
    }
  }
}

// ---------------- conv3: 256->1024, 3x3 s2, pad after=1, K=2304 -> (i,p,oc) f32 ----------------
// FROZEN at the r8 measured-best (118us, MfmaUtil 40%, FETCH 65MB): 1 image x
// 512 oc x 8 waves; image staged in TWO ic-halves (50,432B LDS); acc persists.
// r10 falsified the occupancy path: 4-quarter split raised occupancy 21->31%
// but 4x'd activation traffic (FETCH 65->165MB) -> HBM-bound, 194us. The
// traffic-minimal block is register-quantized to 2 waves/SIMD (188 total regs,
// 512-thr granularity) -> this is the structural optimum for this tiling.
__global__ __launch_bounds__(512, 2) void k_conv3m(const u16* __restrict__ X, // c2o [i][196][256]
                                                   const u16* __restrict__ W, // W3f frag layout
                                                   float* __restrict__ out3) {
  __shared__ u16x8 sX8[3152];          // 196x16 chunks + zero row @3136; 50,432 B
  int bid = blockIdx.x;                // 768
  int og = (bid >> 2) & 1;             // XCDs 0-3 -> og 0, XCDs 4-7 -> og 1
  int i  = (bid >> 3) * 4 + (bid & 3); // bijective over 384 per og
  int tid = threadIdx.x;
  int wv = tid >> 6, lane = tid & 63;

  const u16* src = X + (size_t)i * 50176;   // u16 units; 6272 16B-chunks total

  // stage half h: 3136 chunks (49 groups of 64), pre-swizzled source -> linear LDS
  auto stage = [&](int h) {
    #pragma unroll
    for (int j = 0; j < 7; j++) {
      int gi = wv + j * 8;               // wave-uniform
      if (gi < 49) {
        int slot = gi * 64 + lane;       // 0..3135
        int p = slot >> 4, cq = slot & 15;
        int ih = p / 14, iw = p - ih * 14;
        int g = (7 * (ih >> 1) + (iw >> 1)) & 15;
        int gc = p * 32 + h * 16 + (cq ^ g);
        __builtin_amdgcn_global_load_lds(
            (const __attribute__((address_space(1))) void*)(src + (size_t)gc * 8),
            (__attribute__((address_space(3))) void*)(sX8 + gi * 64),
            16, 0, 0);
      }
    }
  };

  stage(0);
  if (tid < 16) sX8[3136 + tid] = (u16x8){0,0,0,0,0,0,0,0};  // zero row (once)

  int m = lane & 15, quad = lane >> 4;
  int ocw = og * 512 + wv * 64;
  int narr[4], oh2[4], ow2[4];
  #pragma unroll
  for (int nt = 0; nt < 4; nt++) {
    int n = nt * 16 + m;
    narr[nt] = n;
    int nc = n < 49 ? n : 48;
    int oh = nc / 7, ow = nc - oh * 7;
    oh2[nt] = oh * 2; ow2[nt] = ow * 2;
  }
  f32x4 acc[4][4];
  #pragma unroll
  for (int t = 0; t < 4; t++)
    #pragma unroll
    for (int nt = 0; nt < 4; nt++) acc[t][nt] = (f32x4){0.f, 0.f, 0.f, 0.f};

  const u16* wbase = W + (size_t)(ocw >> 4) * (288 * 128) + m * 8;

  int bc[4], bk[4];
  auto set_bparams = [&](int rk) {
    const int r = rk / 3, kw = rk % 3;
    #pragma unroll
    for (int nt = 0; nt < 4; nt++) {
      int ih = oh2[nt] + r, iw = ow2[nt] + kw;
      bool valid = (narr[nt] < 49) && (ih < 14) && (iw < 14);
      int p = ih * 14 + iw;
      bc[nt] = valid ? p * 16 : 3136;
      bk[nt] = valid ? ((7 * (ih >> 1) + (iw >> 1)) & 15) : 0;
    }
  };
  // half h, step s in [0,36): rk = s>>2; K-8-unit = h*16 + (s&3)*4 + quad
  auto loadA = [&](int t, int s, int h) {
    int kblk = (s >> 2) * 32 + h * 16 + (s & 3) * 4 + quad;
    return as_b(*(const u16x8*)(wbase + (size_t)(t * 288 + kblk) * 128));
  };
  auto loadB = [&](int nt, int s) {
    int q = (s & 3) * 4 + quad;          // within-half chunk [0,16)
    return as_b(sX8[bc[nt] + (q ^ bk[nt])]);
  };

  bf16x8 A_[3][4], B_[2][4];

  #pragma unroll
  for (int h = 0; h < 2; h++) {
    __syncthreads();                     // stage(h) data landed (barrier drains DMA)
    set_bparams(0);
    #pragma unroll
    for (int t = 0; t < 4; t++) { A_[0][t] = loadA(t, 0, h); A_[1][t] = loadA(t, 1, h); }
    #pragma unroll
    for (int nt = 0; nt < 4; nt++) B_[0][nt] = loadB(nt, 0);

    #pragma unroll
    for (int s = 0; s < 36; s++) {
      if (s + 2 < 36) {
        #pragma unroll
        for (int t = 0; t < 4; t++) A_[(s + 2) % 3][t] = loadA(t, s + 2, h);
      }
      if (s + 1 < 36) {
        if (((s + 1) & 3) == 0) set_bparams((s + 1) >> 2);
        #pragma unroll
        for (int nt = 0; nt < 4; nt++) B_[(s + 1) & 1][nt] = loadB(nt, s + 1);
      }
      #pragma unroll
      for (int nt = 0; nt < 4; nt++)
        #pragma unroll
        for (int t = 0; t < 4; t++)
          acc[t][nt] = __builtin_amdgcn_mfma_f32_16x16x32_bf16(A_[s % 3][t], B_[s & 1][nt], acc[t][nt], 0, 0, 0);
    }
    if (h == 0) {
      __syncthreads();                   // all waves done reading half 0
      stage(1);                          // restage; next-loop barrier drains
    }
  }

  #pragma unroll
  for (int nt = 0; nt < 4; nt++) {
    int n = narr[nt];
    if (n < 49) {
      #pragma unroll
      for (int t = 0; t < 4; t++) {
        f32x4 o;
        #pragma unroll
        for (int r4 = 0; r4 < 4; r4++) o[r4] = fmaxf(acc[t][nt][r4], 0.f);
        *(f32x4*)(out3 + ((size_t)i * 49 + n) * DIMN + ocw + t * 16 + quad * 4) = o;
      }
    }
  }
}

// ---------------- tokens: mean + concat + pos ----------------
__global__ __launch_bounds__(256) void k_tok(const float* __restrict__ h,   // (384,49,1024)
                                             const float* __restrict__ pos, // (50,1024)
                                             float* __restrict__ tok) {     // (384,50,1024)
  int blk = blockIdx.x;               // 384*50
  int i = blk / 50, t = blk % 50;
  int d = threadIdx.x * 4;
  float4 val;
  if (t == 0) {
    float sx = 0, sy = 0, sz = 0, sw = 0;
    for (int p = 0; p < 49; p++) {
      float4 v = *(const float4*)(h + ((size_t)i * 49 + p) * DIMN + d);
      sx += v.x; sy += v.y; sz += v.z; sw += v.w;
    }
    const float inv49 = 1.0f / 49.0f;
    val.x = sx * inv49; val.y = sy * inv49; val.z = sz * inv49; val.w = sw * inv49;
  } else {
    val = *(const float4*)(h + ((size_t)i * 49 + (t - 1)) * DIMN + d);
  }
  float4 pe = *(const float4*)(pos + (size_t)t * DIMN + d);
  float4 o; o.x = val.x + pe.x; o.y = val.y + pe.y; o.z = val.z + pe.z; o.w = val.w + pe.w;
  *(float4*)(tok + ((size_t)i * 50 + t) * DIMN + d) = o;
}

// ---------------- batched matvec: out[i,:] = vec[i,:] @ M ----------------
// v2: 4-way column split (grid 96x4 = 384 blocks; was 96x2=192 -> <1 block/CU
// across 4 serial launches). 1 f32 col/thread; same total M traffic.
__global__ __launch_bounds__(256) void k_matvec2(const float* __restrict__ vecs, int vstride,
                                                 const float* __restrict__ M,
                                                 float* __restrict__ out) {
  __shared__ float s_v[4][DIMN];
  int i0 = blockIdx.x * 4;
  int h = blockIdx.y;                  // 0..3
  for (int e = threadIdx.x; e < 4 * DIMN; e += 256)
    s_v[e >> 10][e & 1023] = vecs[(size_t)(i0 + (e >> 10)) * vstride + (e & 1023)];
  __syncthreads();
  int d0 = h * 256 + threadIdx.x;
  float acc[4] = {0.f, 0.f, 0.f, 0.f};
  for (int e = 0; e < DIMN; e++) {
    float w = M[(size_t)e * DIMN + d0];
    #pragma unroll
    for (int im = 0; im < 4; im++) acc[im] += s_v[im][e] * w;
  }
  #pragma unroll
  for (int im = 0; im < 4; im++)
    out[(size_t)(i0 + im) * DIMN + d0] = acc[im];
}

// ---------------- scores + softmax + attn-weighted token mix ----------------
__global__ __launch_bounds__(256) void k_attn(const float* __restrict__ tok,
                                              const float* __restrict__ a1,
                                              float* __restrict__ tvec) {
  __shared__ float s_a[DIMN];
  __shared__ float s_sc[50];
  __shared__ float s_at[50];
  int i = blockIdx.x;
  for (int e = threadIdx.x; e < DIMN; e += 256) s_a[e] = a1[(size_t)i * DIMN + e];
  __syncthreads();
  int wave = threadIdx.x >> 6, lane = threadIdx.x & 63;
  for (int t = wave; t < 50; t += 4) {
    const float* tr = tok + ((size_t)i * 50 + t) * DIMN;
    float p = 0.0f;
    for (int mm = 0; mm < 16; mm++) {
      int e = lane + mm * 64;
      p += tr[e] * s_a[e];
    }
    for (int off = 32; off > 0; off >>= 1) p += __shfl_down(p, off, 64);
    if (lane == 0) s_sc[t] = p * 0.03125f;  // DIM^-0.5
  }
  __syncthreads();
  if (threadIdx.x == 0) {
    float mx = s_sc[0];
    for (int t = 1; t < 50; t++) mx = fmaxf(mx, s_sc[t]);
    float sum = 0.0f;
    for (int t = 0; t < 50; t++) { float ex = expf(s_sc[t] - mx); s_at[t] = ex; sum += ex; }
    float inv = 1.0f / sum;
    for (int t = 0; t < 50; t++) s_at[t] *= inv;
  }
  __syncthreads();
  int d0 = threadIdx.x * 4;
  float ax = 0, ay = 0, az = 0, aw = 0;
  for (int t = 0; t < 50; t++) {
    float at = s_at[t];
    float4 tv = *(const float4*)(tok + ((size_t)i * 50 + t) * DIMN + d0);
    ax += at * tv.x; ay += at * tv.y; az += at * tv.z; aw += at * tv.w;
  }
  float4 o; o.x = ax; o.y = ay; o.z = az; o.w = aw;
  *(float4*)(tvec + (size_t)i * DIMN + d0) = o;
}

// ---------------- final momentum merge ----------------
__global__ void k_final(const float* __restrict__ emb,
                        const int* __restrict__ valid,
                        const float* __restrict__ bdd,
                        const float* __restrict__ momp,
                        float* __restrict__ out) {
  int n = blockIdx.x;
  int d0 = threadIdx.x * 4;
  float mom = momp[0];
  float e[4];
  #pragma unroll
  for (int j = 0; j < 4; j++) e[j] = bdd[d0 + j];
  const int order[6] = {2, 0, 1, 5, 3, 4};
  #pragma unroll
  for (int s = 0; s < 6; s++) {
    int c = order[s];
    int i = n * NCAM + c;
    if (valid[i]) {
      const float* er = emb + (size_t)i * DIMN + d0;
      #pragma unroll
      for (int j = 0; j < 4; j++) e[j] = mom * e[j] + (1.0f - mom) * er[j];
    }
  }
  #pragma unroll
  for (int j = 0; j < 4; j++) out[(size_t)n * DIMN + d0 + j] = e[j];
}

extern "C" void kernel_launch(void* const* d_in, const int* in_sizes, int n_in,
                              void* d_out, int out_size, void* d_ws, size_t ws_size,
                              hipStream_t stream) {
  const float* in_cam = (const float*)d_in[0];
  const float* in_box = (const float*)d_in[1];
  const float* in_aug = (const float*)d_in[2];
  const float* in_la  = (const float*)d_in[3];
  const float* in_l2i = (const float*)d_in[4];
  const float* in_mom = (const float*)d_in[5];
  const float* in_bdd = (const float*)d_in[6];
  const float* in_tw  = (const float*)d_in[7];
  const float* in_tb  = (const float*)d_in[8];
  const float* in_c1  = (const float*)d_in[9];
  const float* in_c2  = (const float*)d_in[10];
  const float* in_c3  = (const float*)d_in[11];
  const float* in_pe  = (const float*)d_in[12];
  const float* in_wq  = (const float*)d_in[13];
  const float* in_wk  = (const float*)d_in[14];
  const float* in_wv  = (const float*)d_in[15];
  const float* in_wo  = (const float*)d_in[16];

  char* base = (char*)d_ws;
  size_t off = 0;
  auto carve = [&](size_t bytes) -> char* {
    char* p = base + off;
    off += (bytes + 255) & ~(size_t)255;
    return p;
  };
  float* theta   = (float*)carve((size_t)NIMG * 6 * 4);
  int*   valid   = (int*)carve((size_t)NIMG * 4);
  float* qbuf    = (float*)carve((size_t)NIMG * DIMN * 4);
  float* a1buf   = (float*)carve((size_t)NIMG * DIMN * 4);
  float* tvbuf   = (float*)carve((size_t)NIMG * DIMN * 4);
  float* ctxbuf  = (float*)carve((size_t)NIMG * DIMN * 4);
  float* embbuf  = (float*)carve((size_t)NIMG * DIMN * 4);
  float* wkT_f   = (float*)carve((size_t)DIMN * DIMN * 4);
  u16*   W1r     = (u16*)carve((size_t)64 * 224 * 2);
  u16*   W2r     = (u16*)carve((size_t)256 * 576 * 2);
  u16*   W3r     = (u16*)carve((size_t)1024 * 2304 * 2);
  u16*   c2o     = (u16*)carve((size_t)NIMG * 196 * 256 * 2);
  char*  R1      = carve((size_t)NIMG * 228 * 228 * 4 * 2);   // crops_cl / (conv3o + tok)
  u16*   c1o     = (u16*)carve((size_t)NIMG * 3136 * 64 * 2);
  u16*   crops   = (u16*)R1;
  float* conv3o  = (float*)R1;
  float* tok     = (float*)(R1 + (size_t)NIMG * 49 * DIMN * 4);

  k_w1r<<<56, 256, 0, stream>>>(in_c1, W1r);
  k_w2r<<<576, 256, 0, stream>>>(in_c2, W2r);
  k_w3r<<<9216, 256, 0, stream>>>(in_c3, W3r);
  k_transpose_t<<<dim3(32, 32), dim3(32, 8), 0, stream>>>(in_wk, wkT_f);

  k_proj<<<1, 384, 0, stream>>>(in_box, in_la, in_l2i, in_aug, in_tw, in_tb, theta, valid);
  k_zero_halo<<<(NIMG * HALO_PX + 255) / 256, 256, 0, stream>>>((u16x4*)crops);
  k_sample<<<(NIMG * CROPN * CROPN) / 256, 256, 0, stream>>>(in_cam, theta, crops);
  k_conv1m<<<NIMG * 14, 256, 0, stream>>>(crops, W1r, c1o);
  k_conv2m<<<NIMG * 7, 256, 0, stream>>>(c1o, W2r, c2o);
  k_conv3m<<<768, 512, 0, stream>>>(c2o, W3r, conv3o);
  k_tok<<<NIMG * 50, 256, 0, stream>>>(conv3o, in_pe, tok);
  k_matvec2<<<dim3(96, 4), 256, 0, stream>>>(tok, 50 * DIMN, in_wq, qbuf);
  k_matvec2<<<dim3(96, 4), 256, 0, stream>>>(qbuf, DIMN, wkT_f, a1buf);
  k_attn<<<NIMG, 256, 0, stream>>>(tok, a1buf, tvbuf);
  k_matvec2<<<dim3(96, 4), 256, 0, stream>>>(tvbuf, DIMN, in_wv, ctxbuf);
  k_matvec2<<<dim3(96, 4), 256, 0, stream>>>(ctxbuf, DIMN, in_wo, embbuf);
  k_final<<<NBOX, 256, 0, stream>>>(embbuf, valid, in_bdd, in_mom, (float*)d_out);
}